// Round 1
// baseline (193.203 us; speedup 1.0000x reference)
//
#include <hip/hip_runtime.h>

// NegSamplingWord2Vec: losses[b] = sum_w mask(o_idx[b,w]!=0) *
//   ( softplus(-dot(c_b, o_{b,w})) + sum_k softplus(dot(c_b, neg_{b,w,k})) )
//
// Layout: one block of 640 threads (10 waves) per batch element.
// Wave w handles outside word w: 1 outside row + K negative rows.
// Row = 128 f32 = 512 B -> 64 lanes x float2, perfectly coalesced.

#define WORD_DIM 128
#define W_CTX 10
#define K_NEG 10

__device__ __forceinline__ float softplus(float x) {
    // log(1 + exp(x)), numerically stable
    return fmaxf(x, 0.0f) + log1pf(expf(-fabsf(x)));
}

__device__ __forceinline__ float wave_reduce_sum(float v) {
#pragma unroll
    for (int off = 32; off > 0; off >>= 1)
        v += __shfl_xor(v, off, 64);
    return v;
}

__global__ __launch_bounds__(W_CTX * 64) void w2v_neg_sampling_kernel(
    const float* __restrict__ center_vectors,
    const float* __restrict__ outside_vectors,
    const int*   __restrict__ center_word_index,
    const int*   __restrict__ outside_word_indices,
    const int*   __restrict__ negative_samples,
    float*       __restrict__ out)
{
    const int b    = blockIdx.x;
    const int tid  = threadIdx.x;
    const int wid  = tid >> 6;    // 0..9, which outside word
    const int lane = tid & 63;

    __shared__ float partials[W_CTX];

    // center row: same row for all 10 waves -> L1 hit after first wave
    const int ci = center_word_index[b];
    const float2 c2 = *reinterpret_cast<const float2*>(
        center_vectors + (size_t)ci * WORD_DIM + lane * 2);

    const int oidx = outside_word_indices[b * W_CTX + wid];

    float loss = 0.0f;
    if (oidx != 0) {   // PAD token -> masked out, skip all loads
        const float2 o2 = *reinterpret_cast<const float2*>(
            outside_vectors + (size_t)oidx * WORD_DIM + lane * 2);

        // issue all negative-row loads up front for MLP/ILP
        float2 n2[K_NEG];
        const int* __restrict__ negp =
            negative_samples + ((size_t)b * W_CTX + wid) * K_NEG;
#pragma unroll
        for (int k = 0; k < K_NEG; ++k) {
            const int ni = negp[k];
            n2[k] = *reinterpret_cast<const float2*>(
                outside_vectors + (size_t)ni * WORD_DIM + lane * 2);
        }

        const float s_o = wave_reduce_sum(fmaf(c2.x, o2.x, c2.y * o2.y));
        loss = softplus(-s_o);      // -log_sigmoid(s_o)

#pragma unroll
        for (int k = 0; k < K_NEG; ++k) {
            const float s_k =
                wave_reduce_sum(fmaf(c2.x, n2[k].x, c2.y * n2[k].y));
            loss += softplus(s_k);  // -log_sigmoid(-s_k)
        }
    }

    if (lane == 0) partials[wid] = loss;
    __syncthreads();

    if (tid == 0) {
        float total = 0.0f;
#pragma unroll
        for (int w = 0; w < W_CTX; ++w) total += partials[w];
        out[b] = total;
    }
}

extern "C" void kernel_launch(void* const* d_in, const int* in_sizes, int n_in,
                              void* d_out, int out_size, void* d_ws, size_t ws_size,
                              hipStream_t stream) {
    const float* center_vectors       = (const float*)d_in[0];
    const float* outside_vectors      = (const float*)d_in[1];
    const int*   center_word_index    = (const int*)d_in[2];
    const int*   outside_word_indices = (const int*)d_in[3];
    const int*   negative_samples     = (const int*)d_in[4];
    float*       out                  = (float*)d_out;

    const int batch = in_sizes[2];   // 8192

    w2v_neg_sampling_kernel<<<batch, W_CTX * 64, 0, stream>>>(
        center_vectors, outside_vectors, center_word_index,
        outside_word_indices, negative_samples, out);
}

// Round 2
// 67.850 us; speedup vs baseline: 2.8475x; 2.8475x over previous
//
#include <hip/hip_runtime.h>

// NegSamplingWord2Vec, VALU-optimized layout:
//   losses[b] = sum_w mask(o_idx!=PAD) * ( softplus(-dot(c,o_w)) +
//                                          sum_k softplus(dot(c,neg_wk)) )
//
// One 256-thread block (4 waves) per batch element. All 110 score rows
// (10 words x (1 positive + 10 negatives)) are flattened; each 16-lane
// group owns one row per pass (lane holds 8 floats of the 128-dim row),
// so a wave computes 4 rows per pass with a shared 4-step ds_swizzle
// reduction and ONE softplus instruction sequence covering 4 rows.
// Sign+mask folded into coef c in {-1,0,+1}: loss = |c| * softplus(c*s).

#define D_DIM   128
#define W_CTX   10
#define K_NEG   10
#define NROWS   110          // W_CTX * (1 + K_NEG)
#define NROWS_P 112          // padded to 16*7
#define NPASS   7
#define BLK     256

__device__ __forceinline__ float fast_softplus(float x) {
    // log(1+exp(x)) via hw v_exp_f32 / v_log_f32; |err| ~1e-6 rel, fine here
    return fmaxf(x, 0.0f) + __logf(1.0f + __expf(-fabsf(x)));
}

__global__ __launch_bounds__(BLK) void w2v_neg_sampling_kernel(
    const float* __restrict__ center_vectors,
    const float* __restrict__ outside_vectors,
    const int*   __restrict__ center_word_index,
    const int*   __restrict__ outside_word_indices,
    const int*   __restrict__ negative_samples,
    float*       __restrict__ out)
{
    const int b    = blockIdx.x;
    const int tid  = threadIdx.x;
    const int wave = tid >> 6;
    const int lane = tid & 63;
    const int grp  = lane >> 4;   // 0..3 row-group within wave
    const int gl   = lane & 15;   // lane within 16-lane row group

    __shared__ int   s_idx[NROWS_P];
    __shared__ float s_coef[NROWS_P];
    __shared__ int   s_oidx[W_CTX];
    __shared__ float s_part[4];

    // ---- prologue 1: stage all row indices into LDS ----
    if (tid < W_CTX) {
        const int oi = outside_word_indices[b * W_CTX + tid];
        s_oidx[tid]      = oi;
        s_idx[tid * 11]  = oi;                    // positive row slot
    } else if (tid >= 16 && tid < 16 + W_CTX * K_NEG) {
        const int r = tid - 16;                   // 0..99, coalesced load
        const int w = r / K_NEG;
        const int j = r - w * K_NEG;
        s_idx[w * 11 + 1 + j] = negative_samples[b * W_CTX * K_NEG + r];
    } else if (tid >= 128 && tid < 128 + (NROWS_P - NROWS)) {
        s_idx[NROWS + (tid - 128)] = 0;           // pad rows -> row 0
    }
    __syncthreads();

    // ---- prologue 2: per-row coefficient (sign * mask) ----
    if (tid < NROWS_P) {
        float coef = 0.0f;
        if (tid < NROWS) {
            const int w = tid / 11;
            const int j = tid - w * 11;
            coef = (s_oidx[w] != 0) ? ((j == 0) ? -1.0f : 1.0f) : 0.0f;
        }
        s_coef[tid] = coef;
    }
    __syncthreads();

    // ---- center row fragment: 8 floats per lane (16 lanes cover row) ----
    const int ci = center_word_index[b];
    const float4* cp = reinterpret_cast<const float4*>(
        center_vectors + (size_t)ci * D_DIM + gl * 8);
    const float4 c0 = cp[0];
    const float4 c1 = cp[1];

    float acc = 0.0f;

#pragma unroll
    for (int p = 0; p < NPASS; ++p) {
        const int r   = p * 16 + wave * 4 + grp;      // unique row in [0,112)
        const int idx = s_idx[r];
        const float cf = s_coef[r];

        const float4* rp = reinterpret_cast<const float4*>(
            outside_vectors + (size_t)idx * D_DIM + gl * 8);
        const float4 a0 = rp[0];
        const float4 a1 = rp[1];

        float s = c0.x * a0.x;
        s = fmaf(c0.y, a0.y, s);
        s = fmaf(c0.z, a0.z, s);
        s = fmaf(c0.w, a0.w, s);
        s = fmaf(c1.x, a1.x, s);
        s = fmaf(c1.y, a1.y, s);
        s = fmaf(c1.z, a1.z, s);
        s = fmaf(c1.w, a1.w, s);

        // reduce across the 16-lane group (ds_swizzle path, masks < 32)
        s += __shfl_xor(s, 8, 64);
        s += __shfl_xor(s, 4, 64);
        s += __shfl_xor(s, 2, 64);
        s += __shfl_xor(s, 1, 64);

        // one softplus sequence covers 4 rows (different value per group)
        acc += fabsf(cf) * fast_softplus(cf * s);
    }

    // acc is uniform within each 16-lane group; sum the 4 groups
    acc += __shfl_xor(acc, 16, 64);
    acc += __shfl_xor(acc, 32, 64);

    if (lane == 0) s_part[wave] = acc;
    __syncthreads();

    if (tid == 0)
        out[b] = s_part[0] + s_part[1] + s_part[2] + s_part[3];
}

extern "C" void kernel_launch(void* const* d_in, const int* in_sizes, int n_in,
                              void* d_out, int out_size, void* d_ws, size_t ws_size,
                              hipStream_t stream) {
    const float* center_vectors       = (const float*)d_in[0];
    const float* outside_vectors      = (const float*)d_in[1];
    const int*   center_word_index    = (const int*)d_in[2];
    const int*   outside_word_indices = (const int*)d_in[3];
    const int*   negative_samples     = (const int*)d_in[4];
    float*       out                  = (float*)d_out;

    const int batch = in_sizes[2];   // 8192

    w2v_neg_sampling_kernel<<<batch, BLK, 0, stream>>>(
        center_vectors, outside_vectors, center_word_index,
        outside_word_indices, negative_samples, out);
}

// Round 3
// 65.574 us; speedup vs baseline: 2.9463x; 1.0347x over previous
//
#include <hip/hip_runtime.h>

// NegSamplingWord2Vec, latency-optimized:
//   losses[b] = sum_w mask(o_idx!=PAD) * ( softplus(-dot(c,o_w)) +
//                                          sum_k softplus(dot(c,neg_wk)) )
//
// One 256-thread block (4 waves) per batch element. 110 score rows
// (10 words x (1 pos + 10 neg)) padded to 112 = 16 groups x 7 passes.
// Each 16-lane group owns one row per pass; lane gl holds contiguous
// float4 fragments row[gl*4] and row[64+gl*4] (permutation-invariant dot),
// so every VMEM instruction is a fully-contiguous 256 B segment.
// ALL 14 row loads are issued before the compute loop (static reg arrays)
// so the 7 reduce+softplus chains drain against in-flight loads.

#define D_DIM   128
#define W_CTX   10
#define K_NEG   10
#define NROWS   110
#define NROWS_P 112
#define NPASS   7
#define BLK     256

__device__ __forceinline__ float fast_softplus(float x) {
    // log(1+exp(x)) via hw v_exp_f32 / v_log_f32
    return fmaxf(x, 0.0f) + __logf(1.0f + __expf(-fabsf(x)));
}

__global__ __launch_bounds__(BLK) void w2v_neg_sampling_kernel(
    const float* __restrict__ center_vectors,
    const float* __restrict__ outside_vectors,
    const int*   __restrict__ center_word_index,
    const int*   __restrict__ outside_word_indices,
    const int*   __restrict__ negative_samples,
    float*       __restrict__ out)
{
    const int b    = blockIdx.x;
    const int tid  = threadIdx.x;
    const int wave = tid >> 6;
    const int lane = tid & 63;
    const int grp  = lane >> 4;   // 0..3 row-group within wave
    const int gl   = lane & 15;   // lane within 16-lane row group

    __shared__ int   s_idx[NROWS_P];
    __shared__ float s_part[4];

    // ---- stage row indices into LDS (slot w*11 = positive/oidx) ----
    if (tid < W_CTX) {
        s_idx[tid * 11] = outside_word_indices[b * W_CTX + tid];
    } else if (tid >= 16 && tid < 16 + W_CTX * K_NEG) {
        const int r = tid - 16;                   // 0..99, coalesced
        const int w = r / K_NEG;
        const int j = r - w * K_NEG;
        s_idx[w * 11 + 1 + j] = negative_samples[b * W_CTX * K_NEG + r];
    } else if (tid >= 128 && tid < 128 + (NROWS_P - NROWS)) {
        s_idx[NROWS + (tid - 128)] = 0;           // pad rows -> row 0
    }
    __syncthreads();

    // ---- center fragment: contiguous float4 pair ----
    const int ci = center_word_index[b];
    const float4* cp = reinterpret_cast<const float4*>(
        center_vectors + (size_t)ci * D_DIM);
    const float4 c0 = cp[gl];
    const float4 c1 = cp[16 + gl];

    // ---- gather my 7 row ids + coefficients ----
    int   idxs[NPASS];
    float cfs[NPASS];
#pragma unroll
    for (int p = 0; p < NPASS; ++p) {
        const int r = p * 16 + wave * 4 + grp;    // unique row in [0,112)
        const int w = r / 11;
        const int j = r - w * 11;
        idxs[p] = s_idx[r];
        const int oi = s_idx[w * 11];             // positive slot = oidx (0 for pads)
        cfs[p] = (oi != 0) ? ((j == 0) ? -1.0f : 1.0f) : 0.0f;
    }

    // ---- issue ALL 14 row-fragment loads up front ----
    float4 a0[NPASS], a1[NPASS];
#pragma unroll
    for (int p = 0; p < NPASS; ++p) {
        const float4* rp = reinterpret_cast<const float4*>(
            outside_vectors + (size_t)idxs[p] * D_DIM);
        a0[p] = rp[gl];
        a1[p] = rp[16 + gl];
    }

    // ---- compute: dot + 16-lane reduce + softplus per pass ----
    float acc = 0.0f;
#pragma unroll
    for (int p = 0; p < NPASS; ++p) {
        float s = c0.x * a0[p].x;
        s = fmaf(c0.y, a0[p].y, s);
        s = fmaf(c0.z, a0[p].z, s);
        s = fmaf(c0.w, a0[p].w, s);
        s = fmaf(c1.x, a1[p].x, s);
        s = fmaf(c1.y, a1[p].y, s);
        s = fmaf(c1.z, a1[p].z, s);
        s = fmaf(c1.w, a1[p].w, s);

        s += __shfl_xor(s, 8, 64);
        s += __shfl_xor(s, 4, 64);
        s += __shfl_xor(s, 2, 64);
        s += __shfl_xor(s, 1, 64);

        acc += fabsf(cfs[p]) * fast_softplus(cfs[p] * s);
    }

    // acc uniform within each 16-lane group; sum the 4 groups, then 4 waves
    acc += __shfl_xor(acc, 16, 64);
    acc += __shfl_xor(acc, 32, 64);

    if (lane == 0) s_part[wave] = acc;
    __syncthreads();

    if (tid == 0)
        out[b] = s_part[0] + s_part[1] + s_part[2] + s_part[3];
}

extern "C" void kernel_launch(void* const* d_in, const int* in_sizes, int n_in,
                              void* d_out, int out_size, void* d_ws, size_t ws_size,
                              hipStream_t stream) {
    const float* center_vectors       = (const float*)d_in[0];
    const float* outside_vectors      = (const float*)d_in[1];
    const int*   center_word_index    = (const int*)d_in[2];
    const int*   outside_word_indices = (const int*)d_in[3];
    const int*   negative_samples     = (const int*)d_in[4];
    float*       out                  = (float*)d_out;

    const int batch = in_sizes[2];   // 8192

    w2v_neg_sampling_kernel<<<batch, BLK, 0, stream>>>(
        center_vectors, outside_vectors, center_word_index,
        outside_word_indices, negative_samples, out);
}

// Round 4
// 65.449 us; speedup vs baseline: 2.9519x; 1.0019x over previous
//
#include <hip/hip_runtime.h>

// NegSamplingWord2Vec, latency-optimized v2:
//   losses[b] = sum_w mask(o_idx!=PAD) * ( softplus(-dot(c,o_w)) +
//                                          sum_k softplus(dot(c,neg_wk)) )
//
// One 256-thread block (4 waves) per batch element. 110 score rows
// (10 words x (1 pos + 10 neg)) padded to 112 = 16 groups x 7 passes.
// Each 16-lane group owns one row per pass; lane gl holds contiguous
// float4 fragments row[gl*4] and row[64+gl*4] (dot is permutation-
// invariant), so every VMEM instruction is a contiguous 256 B segment.
//
// v2: __builtin_amdgcn_sched_barrier(0) between the load loop and the
// compute loop. Round-3 codegen (VGPR=36) showed the compiler sinking
// the "prefetched" loads back next to their uses, serializing 7
// load-use chains; the sched_barrier pins all 14 global_load_dwordx4
// before any compute so they are simultaneously in flight.

#define D_DIM   128
#define W_CTX   10
#define K_NEG   10
#define NROWS   110
#define NROWS_P 112
#define NPASS   7
#define BLK     256

__device__ __forceinline__ float fast_softplus(float x) {
    // log(1+exp(x)) via hw v_exp_f32 / v_log_f32
    return fmaxf(x, 0.0f) + __logf(1.0f + __expf(-fabsf(x)));
}

__global__ __launch_bounds__(BLK) void w2v_neg_sampling_kernel(
    const float* __restrict__ center_vectors,
    const float* __restrict__ outside_vectors,
    const int*   __restrict__ center_word_index,
    const int*   __restrict__ outside_word_indices,
    const int*   __restrict__ negative_samples,
    float*       __restrict__ out)
{
    const int b    = blockIdx.x;
    const int tid  = threadIdx.x;
    const int wave = tid >> 6;
    const int lane = tid & 63;
    const int grp  = lane >> 4;   // 0..3 row-group within wave
    const int gl   = lane & 15;   // lane within 16-lane row group

    __shared__ int   s_idx[NROWS_P];
    __shared__ float s_part[4];

    // ---- stage row indices into LDS (slot w*11 = positive/oidx) ----
    if (tid < W_CTX) {
        s_idx[tid * 11] = outside_word_indices[b * W_CTX + tid];
    } else if (tid >= 16 && tid < 16 + W_CTX * K_NEG) {
        const int r = tid - 16;                   // 0..99, coalesced
        const int w = r / K_NEG;
        const int j = r - w * K_NEG;
        s_idx[w * 11 + 1 + j] = negative_samples[b * W_CTX * K_NEG + r];
    } else if (tid >= 128 && tid < 128 + (NROWS_P - NROWS)) {
        s_idx[NROWS + (tid - 128)] = 0;           // pad rows -> row 0
    }
    __syncthreads();

    // ---- center fragment: contiguous float4 pair ----
    const int ci = center_word_index[b];
    const float4* cp = reinterpret_cast<const float4*>(
        center_vectors + (size_t)ci * D_DIM);
    const float4 c0 = cp[gl];
    const float4 c1 = cp[16 + gl];

    // ---- gather my 7 row ids + coefficients ----
    int   idxs[NPASS];
    float cfs[NPASS];
#pragma unroll
    for (int p = 0; p < NPASS; ++p) {
        const int r = p * 16 + wave * 4 + grp;    // unique row in [0,112)
        const int w = r / 11;
        const int j = r - w * 11;
        idxs[p] = s_idx[r];
        const int oi = s_idx[w * 11];             // positive slot = oidx (0 for pads)
        cfs[p] = (oi != 0) ? ((j == 0) ? -1.0f : 1.0f) : 0.0f;
    }

    // ---- issue ALL 14 row-fragment loads; pin them before compute ----
    float4 a0[NPASS], a1[NPASS];
#pragma unroll
    for (int p = 0; p < NPASS; ++p) {
        const float4* rp = reinterpret_cast<const float4*>(
            outside_vectors + (size_t)idxs[p] * D_DIM);
        a0[p] = rp[gl];
        a1[p] = rp[16 + gl];
    }
    // Hard scheduling fence: nothing moves across. All 14 VMEM loads are
    // issued before any compute below; they retire against vmcnt as the
    // dot/softplus chains consume them in order.
    __builtin_amdgcn_sched_barrier(0);

    // ---- compute: dot + 16-lane reduce + softplus per pass ----
    float acc = 0.0f;
#pragma unroll
    for (int p = 0; p < NPASS; ++p) {
        float s = c0.x * a0[p].x;
        s = fmaf(c0.y, a0[p].y, s);
        s = fmaf(c0.z, a0[p].z, s);
        s = fmaf(c0.w, a0[p].w, s);
        s = fmaf(c1.x, a1[p].x, s);
        s = fmaf(c1.y, a1[p].y, s);
        s = fmaf(c1.z, a1[p].z, s);
        s = fmaf(c1.w, a1[p].w, s);

        s += __shfl_xor(s, 8, 64);
        s += __shfl_xor(s, 4, 64);
        s += __shfl_xor(s, 2, 64);
        s += __shfl_xor(s, 1, 64);

        acc += fabsf(cfs[p]) * fast_softplus(cfs[p] * s);
    }

    // acc uniform within each 16-lane group; sum the 4 groups, then 4 waves
    acc += __shfl_xor(acc, 16, 64);
    acc += __shfl_xor(acc, 32, 64);

    if (lane == 0) s_part[wave] = acc;
    __syncthreads();

    if (tid == 0)
        out[b] = s_part[0] + s_part[1] + s_part[2] + s_part[3];
}

extern "C" void kernel_launch(void* const* d_in, const int* in_sizes, int n_in,
                              void* d_out, int out_size, void* d_ws, size_t ws_size,
                              hipStream_t stream) {
    const float* center_vectors       = (const float*)d_in[0];
    const float* outside_vectors      = (const float*)d_in[1];
    const int*   center_word_index    = (const int*)d_in[2];
    const int*   outside_word_indices = (const int*)d_in[3];
    const int*   negative_samples     = (const int*)d_in[4];
    float*       out                  = (float*)d_out;

    const int batch = in_sizes[2];   // 8192

    w2v_neg_sampling_kernel<<<batch, BLK, 0, stream>>>(
        center_vectors, outside_vectors, center_word_index,
        outside_word_indices, negative_samples, out);
}